// Round 1
// baseline (206.353 us; speedup 1.0000x reference)
//
#include <hip/hip_runtime.h>

#define EMB 512
#define NROWS 10000
#define NPAIRS 65536

// ---------------- Kernel 1: D = drug @ W1[:512,:], T = tgt @ W1[512:,:] ----------------
// Also (block 314) transposes W2 (128x64) -> W2t (64x128) into workspace.
#define K1_BM 64
#define K1_BK 32
#define K1_BLOCKS_PER_TABLE 157  // ceil(10000/64)

__global__ __launch_bounds__(256)
void k1_precompute(const float* __restrict__ drug, const float* __restrict__ tgt,
                   const float* __restrict__ W1, const float* __restrict__ W2,
                   float* __restrict__ D, float* __restrict__ T, float* __restrict__ W2t)
{
    __shared__ float As[K1_BK][K1_BM + 4];   // [kk][row] transposed, stride 68
    __shared__ float Bs[K1_BK][128 + 4];     // [kk][col], stride 132

    int bid = blockIdx.x;
    int tid = threadIdx.x;

    if (bid == 2 * K1_BLOCKS_PER_TABLE) {
        // transpose W2 into W2t[c][k] = W2[k][c]
        for (int e = tid; e < 128 * 64; e += 256) {
            int k = e >> 6, c = e & 63;          // consecutive lanes -> consecutive c (coalesced read)
            W2t[c * 128 + k] = W2[k * 64 + c];
        }
        return;
    }

    bool isT = bid >= K1_BLOCKS_PER_TABLE;
    int tb = isT ? bid - K1_BLOCKS_PER_TABLE : bid;
    const float* emb = isT ? tgt : drug;
    const float* Wb  = W1 + (isT ? EMB * 128 : 0);
    float* out = isT ? T : D;
    int row0 = tb * K1_BM;

    float acc[8][4];
    #pragma unroll
    for (int i = 0; i < 8; i++)
        #pragma unroll
        for (int j = 0; j < 4; j++) acc[i][j] = 0.f;

    int trow0 = (tid >> 5) * 8;   // 0..56
    int tcol0 = (tid & 31) * 4;   // 0..124

    for (int k0 = 0; k0 < EMB; k0 += K1_BK) {
        __syncthreads();
        // A tile: 64 rows x 32 k = 512 float4; 2 per thread, stored transposed
        #pragma unroll
        for (int l = 0; l < 2; l++) {
            int e = tid + l * 256;
            int r = e >> 3, k4 = e & 7;
            int gr = row0 + r;
            float4 v = make_float4(0.f, 0.f, 0.f, 0.f);
            if (gr < NROWS) v = *(const float4*)(emb + gr * EMB + k0 + k4 * 4);
            As[k4 * 4 + 0][r] = v.x; As[k4 * 4 + 1][r] = v.y;
            As[k4 * 4 + 2][r] = v.z; As[k4 * 4 + 3][r] = v.w;
        }
        // B tile: 32 k x 128 c = 1024 float4; 4 per thread
        #pragma unroll
        for (int l = 0; l < 4; l++) {
            int e = tid + l * 256;
            int kk = e >> 5, c4 = e & 31;
            *(float4*)&Bs[kk][c4 * 4] = *(const float4*)(Wb + (k0 + kk) * 128 + c4 * 4);
        }
        __syncthreads();
        #pragma unroll
        for (int kk = 0; kk < K1_BK; kk++) {
            float4 a0 = *(const float4*)&As[kk][trow0];
            float4 a1 = *(const float4*)&As[kk][trow0 + 4];
            float4 b  = *(const float4*)&Bs[kk][tcol0];
            float av[8] = {a0.x, a0.y, a0.z, a0.w, a1.x, a1.y, a1.z, a1.w};
            float bv[4] = {b.x, b.y, b.z, b.w};
            #pragma unroll
            for (int i = 0; i < 8; i++)
                #pragma unroll
                for (int j = 0; j < 4; j++)
                    acc[i][j] = fmaf(av[i], bv[j], acc[i][j]);
        }
    }
    #pragma unroll
    for (int i = 0; i < 8; i++) {
        int gr = row0 + trow0 + i;
        if (gr < NROWS)
            *(float4*)(out + gr * 128 + tcol0) =
                make_float4(acc[i][0], acc[i][1], acc[i][2], acc[i][3]);
    }
}

// ---------------- Kernel 2: pair loss ----------------
// 512 blocks x 256 threads. Per wave: batch of 32 pairs = 64 rows (2 sides) x 64 cols, K=128.
// A (h1) in wave-private LDS [64 rows][64 k] per K-half, XOR-swizzled for conflict-free b128.
// W2t read from global (L2-resident). Per-lane 8x8 micro-tile: lane = cb + 8*rb.
__global__ __launch_bounds__(256, 2)
void k2_pairs(const float* __restrict__ D, const float* __restrict__ T,
              const int* __restrict__ pos, const int* __restrict__ neg,
              const float* __restrict__ b1, const float* __restrict__ W2t,
              const float* __restrict__ b2, const float* __restrict__ W3,
              double* __restrict__ partials)
{
    __shared__ float Asmem[4][64 * 64];   // 64 KB total, wave-private quarters

    int tid  = threadIdx.x;
    int wave = tid >> 6, lane = tid & 63;
    int cb = lane & 7, rb = lane >> 3;

    float b2v[8], w3v[8];
    #pragma unroll
    for (int j = 0; j < 8; j++) { b2v[j] = b2[cb * 8 + j]; w3v[j] = W3[cb * 8 + j]; }
    float b1lo = b1[lane], b1hi = b1[64 + lane];

    float* A = &Asmem[wave][0];
    const float4* W2t4 = (const float4*)W2t;   // [64][32] float4
    int gw = blockIdx.x * 4 + wave;            // 0..2047

    double accs[2] = {0.0, 0.0};
    #pragma unroll 1
    for (int set = 0; set < 2; set++) {
        const int* pairs = set ? neg : pos;
        int p0 = gw * 32;   // 2048 batches x 32 pairs = 65536
        float acc[8][8];
        #pragma unroll
        for (int i = 0; i < 8; i++)
            #pragma unroll
            for (int j = 0; j < 8; j++) acc[i][j] = 0.f;

        #pragma unroll
        for (int h = 0; h < 2; h++) {
            float b1v = h ? b1hi : b1lo;
            // phase 1: build h1 rows for k in [64h, 64h+64); lane = k offset
            #pragma unroll 4
            for (int p = 0; p < 32; p++) {
                int i0 = pairs[(p0 + p) * 3 + 0];
                int i1 = pairs[(p0 + p) * 3 + 1];
                int i2 = pairs[(p0 + p) * 3 + 2];
                float d  = D[i0 * 128 + h * 64 + lane];
                float t1 = T[i1 * 128 + h * 64 + lane];
                float t2 = T[i2 * 128 + h * 64 + lane];
                float h1a = fmaxf(d + t1 + b1v, 0.f);
                float h1b = fmaxf(d + t2 + b1v, 0.f);
                int r0 = 2 * p, r1 = 2 * p + 1;
                int s0 = (((lane >> 2) ^ (r0 >> 3)) << 2) | (lane & 3);
                int s1 = (((lane >> 2) ^ (r1 >> 3)) << 2) | (lane & 3);
                A[r0 * 64 + s0] = h1a;   // banks: bijection over 64 dwords -> 2-way, free
                A[r1 * 64 + s1] = h1b;
            }
            // phase 2: 16 k4-steps of 8x8 outer-product (wave-private LDS, no barrier)
            const float4* A4 = (const float4*)A;  // [64][16]
            #pragma unroll 2
            for (int k4 = 0; k4 < 16; k4++) {
                int gk4 = h * 16 + k4;
                float4 av[8], bv[8];
                #pragma unroll
                for (int i = 0; i < 8; i++) av[i] = A4[(rb * 8 + i) * 16 + (k4 ^ rb)];
                #pragma unroll
                for (int j = 0; j < 8; j++) bv[j] = W2t4[(cb * 8 + j) * 32 + gk4];
                #pragma unroll
                for (int i = 0; i < 8; i++)
                    #pragma unroll
                    for (int j = 0; j < 8; j++) {
                        acc[i][j] = fmaf(av[i].x, bv[j].x, acc[i][j]);
                        acc[i][j] = fmaf(av[i].y, bv[j].y, acc[i][j]);
                        acc[i][j] = fmaf(av[i].z, bv[j].z, acc[i][j]);
                        acc[i][j] = fmaf(av[i].w, bv[j].w, acc[i][j]);
                    }
            }
        }
        // epilogue: relu + W3 dot, reduce over cb (lane bits 0..2)
        float pr[8];
        #pragma unroll
        for (int i = 0; i < 8; i++) {
            float s = 0.f;
            #pragma unroll
            for (int j = 0; j < 8; j++) {
                float h2 = fmaxf(acc[i][j] + b2v[j], 0.f);
                s = fmaf(h2, w3v[j], s);
            }
            pr[i] = s;
        }
        #pragma unroll
        for (int m = 1; m <= 4; m <<= 1)
            #pragma unroll
            for (int i = 0; i < 8; i++) pr[i] += __shfl_xor(pr[i], m, 64);
        double s = 0.0;
        #pragma unroll
        for (int e = 0; e < 4; e++) {
            float dff = pr[2 * e] - pr[2 * e + 1];
            s += (double)dff * (double)dff;
        }
        accs[set] += s;
    }
    // sum over rb groups (cb copies are identical); then block-level reduce via LDS alias
    #pragma unroll
    for (int m = 8; m <= 32; m <<= 1) {
        accs[0] += __shfl_xor(accs[0], m, 64);
        accs[1] += __shfl_xor(accs[1], m, 64);
    }
    __syncthreads();   // everyone done with A before aliasing
    if (lane == 0) {
        double* wr = (double*)&Asmem[wave][0];
        wr[0] = accs[0]; wr[1] = accs[1];
    }
    __syncthreads();
    if (tid == 0) {
        double sp = 0.0, sn = 0.0;
        #pragma unroll
        for (int w = 0; w < 4; w++) {
            double* q = (double*)&Asmem[w][0];
            sp += q[0]; sn += q[1];
        }
        partials[blockIdx.x] = sp;
        partials[512 + blockIdx.x] = sn;
    }
}

// ---------------- Kernel 3: final reduction ----------------
__global__ void k3_final(const double* __restrict__ partials, float* __restrict__ out)
{
    int lane = threadIdx.x;  // 64 threads
    double sp = 0.0, sn = 0.0;
    #pragma unroll
    for (int i = 0; i < 8; i++) {
        sp += partials[lane + 64 * i];
        sn += partials[512 + lane + 64 * i];
    }
    #pragma unroll
    for (int m = 1; m <= 32; m <<= 1) {
        sp += __shfl_xor(sp, m, 64);
        sn += __shfl_xor(sn, m, 64);
    }
    if (lane == 0) out[0] = (float)((sp - sn) / (double)NPAIRS);
}

extern "C" void kernel_launch(void* const* d_in, const int* in_sizes, int n_in,
                              void* d_out, int out_size, void* d_ws, size_t ws_size,
                              hipStream_t stream) {
    const int*   pos  = (const int*)d_in[0];
    const int*   neg  = (const int*)d_in[1];
    const float* drug = (const float*)d_in[2];
    const float* tgt  = (const float*)d_in[3];
    const float* W1   = (const float*)d_in[4];
    const float* b1   = (const float*)d_in[5];
    const float* W2   = (const float*)d_in[6];
    const float* b2   = (const float*)d_in[7];
    const float* W3   = (const float*)d_in[8];
    // d_in[9] = b3: cancels in a1 - a2, unused

    float* D   = (float*)d_ws;
    float* T   = D + NROWS * 128;
    float* W2t = T + NROWS * 128;                       // 64*128 floats
    double* partials = (double*)((char*)d_ws +
                       (size_t)(2 * NROWS * 128 + 64 * 128) * sizeof(float)); // 8B-aligned
    float* out = (float*)d_out;

    k1_precompute<<<2 * K1_BLOCKS_PER_TABLE + 1, 256, 0, stream>>>(drug, tgt, W1, W2, D, T, W2t);
    k2_pairs<<<512, 256, 0, stream>>>(D, T, pos, neg, b1, W2t, b2, W3, partials);
    k3_final<<<1, 64, 0, stream>>>(partials, out);
}

// Round 2
// 109.709 us; speedup vs baseline: 1.8809x; 1.8809x over previous
//
#include <hip/hip_runtime.h>

#define EMB 512
#define NROWS 10000
#define NPAIRS 65536

// ---------------- Kernel 1: D = drug @ W1[:512,:], T = tgt @ W1[512:,:] ----------------
// 32-row x 128-col tiles, 313 blocks per table -> 626 blocks (better tail balance).
#define K1_BM 32
#define K1_BK 32
#define K1_BLOCKS 313  // ceil(10000/32)

__global__ __launch_bounds__(256)
void k1_precompute(const float* __restrict__ drug, const float* __restrict__ tgt,
                   const float* __restrict__ W1,
                   float* __restrict__ D, float* __restrict__ T)
{
    __shared__ float As[K1_BK][K1_BM + 4];   // [k][row] transposed, stride 36
    __shared__ float Bs[K1_BK][132];         // [k][col], stride 132

    int bid = blockIdx.x, tid = threadIdx.x;
    bool isT = bid >= K1_BLOCKS;
    int tb = isT ? bid - K1_BLOCKS : bid;
    const float* emb = isT ? tgt : drug;
    const float* Wb  = W1 + (isT ? EMB * 128 : 0);
    float* out = isT ? T : D;
    int row0 = tb * K1_BM;

    float acc[4][4];
    #pragma unroll
    for (int i = 0; i < 4; i++)
        #pragma unroll
        for (int j = 0; j < 4; j++) acc[i][j] = 0.f;

    int trow0 = (tid >> 5) * 4;   // 0..28
    int tcol0 = (tid & 31) * 4;   // 0..124

    for (int k0 = 0; k0 < EMB; k0 += K1_BK) {
        __syncthreads();
        {   // A tile: 32 rows x 32 k = 256 float4, 1 per thread, stored transposed
            int r = tid >> 3, k4 = tid & 7;
            int gr = row0 + r;
            float4 v = make_float4(0.f, 0.f, 0.f, 0.f);
            if (gr < NROWS) v = *(const float4*)(emb + gr * EMB + k0 + k4 * 4);
            As[k4 * 4 + 0][r] = v.x; As[k4 * 4 + 1][r] = v.y;
            As[k4 * 4 + 2][r] = v.z; As[k4 * 4 + 3][r] = v.w;
        }
        // B tile: 32 k x 128 c = 1024 float4, 4 per thread
        #pragma unroll
        for (int l = 0; l < 4; l++) {
            int e = tid + l * 256;
            int kk = e >> 5, c4 = e & 31;
            *(float4*)&Bs[kk][c4 * 4] = *(const float4*)(Wb + (k0 + kk) * 128 + c4 * 4);
        }
        __syncthreads();
        #pragma unroll
        for (int kk = 0; kk < K1_BK; kk++) {
            float4 a = *(const float4*)&As[kk][trow0];
            float4 b = *(const float4*)&Bs[kk][tcol0];
            float av[4] = {a.x, a.y, a.z, a.w};
            float bv[4] = {b.x, b.y, b.z, b.w};
            #pragma unroll
            for (int i = 0; i < 4; i++)
                #pragma unroll
                for (int j = 0; j < 4; j++)
                    acc[i][j] = fmaf(av[i], bv[j], acc[i][j]);
        }
    }
    #pragma unroll
    for (int i = 0; i < 4; i++) {
        int gr = row0 + trow0 + i;
        if (gr < NROWS)
            *(float4*)(out + gr * 128 + tcol0) =
                make_float4(acc[i][0], acc[i][1], acc[i][2], acc[i][3]);
    }
}

// ---------------- Kernel 2: pair loss ----------------
// 1024 blocks x 256 threads (4 waves). Each wave: 32 pairs of ONE set (pos or neg)
// = 64 rows, lane = row. h1 built in K-quarters (32 k) via wave-private 8 KB LDS
// (lane = k on write, lane = row on read, XOR-swizzled float4 chunks).
// Inner loop: acc[c] += h1[k] * W2[k][c] -- W2 index loop-uniform -> scalar loads,
// pure-FMA stream with SGPR B operand. 32 KB LDS/block -> 4 blocks/CU, 16 waves/CU.
__global__ __launch_bounds__(256, 4)
void k2_pairs(const float* __restrict__ D, const float* __restrict__ T,
              const int* __restrict__ pos, const int* __restrict__ neg,
              const float* __restrict__ b1, const float* __restrict__ W2,
              const float* __restrict__ b2, const float* __restrict__ W3,
              double* __restrict__ partials)
{
    __shared__ float Ash[4][64 * 32];   // 32 KB, wave-private 8 KB quarters

    int tid = threadIdx.x;
    int wave = tid >> 6, lane = tid & 63;
    int gw = blockIdx.x * 4 + wave;                 // 0..4095
    const int* pairs = (gw < 2048) ? pos : neg;     // blocks 0..511 pos, 512..1023 neg
    int p0 = (gw & 2047) * 32;                      // 32 pairs per wave

    float* A = &Ash[wave][0];
    int kk = lane & 31, sub = lane >> 5;
    int row = lane, rm = row & 7;

    float acc[64];
    #pragma unroll
    for (int c = 0; c < 64; c++) acc[c] = 0.f;

    #pragma unroll 1
    for (int q = 0; q < 4; q++) {
        float b1v = b1[q * 32 + kk];
        // ---- phase 1: build h1 k-slice [q*32, q*32+32) for 64 rows ----
        // lane covers (sub: which of 2 pairs, kk: k offset); 2 rows per iter per sub.
        #pragma unroll 4
        for (int p2 = 0; p2 < 16; p2++) {
            int p = p0 + p2 * 2 + sub;
            int i0 = pairs[p * 3 + 0];
            int i1 = pairs[p * 3 + 1];
            int i2 = pairs[p * 3 + 2];
            float d  = D[i0 * 128 + q * 32 + kk];
            float t1 = T[i1 * 128 + q * 32 + kk];
            float t2 = T[i2 * 128 + q * 32 + kk];
            float h1a = fmaxf(d + t1 + b1v, 0.f);
            float h1b = fmaxf(d + t2 + b1v, 0.f);
            int r0 = 4 * p2 + 2 * sub, r1 = r0 + 1;
            int cj = kk >> 2, e = kk & 3;
            A[r0 * 32 + (((cj ^ (r0 & 7)) << 2) | e)] = h1a;  // chunk-XOR swizzle
            A[r1 * 32 + (((cj ^ (r1 & 7)) << 2) | e)] = h1b;
        }
        asm volatile("s_waitcnt lgkmcnt(0)" ::: "memory");  // wave-internal transpose fence
        // ---- phase 2: lane = row; acc[c] += h1[k] * W2[k][c], W2 via scalar loads ----
        const float4* A4 = (const float4*)A;
        #pragma unroll 2
        for (int j = 0; j < 8; j++) {
            float4 av = A4[row * 8 + (j ^ rm)];
            float a4[4] = {av.x, av.y, av.z, av.w};
            #pragma unroll
            for (int e = 0; e < 4; e++) {
                const float* wr = W2 + (q * 32 + j * 4 + e) * 64;  // uniform -> s_load
                float a = a4[e];
                #pragma unroll
                for (int c = 0; c < 64; c++)
                    acc[c] = fmaf(a, wr[c], acc[c]);
            }
        }
        asm volatile("s_waitcnt lgkmcnt(0)" ::: "memory");  // reads done before next overwrite
    }

    // ---- epilogue: layer 3 + pair diff ----
    float s = 0.f;
    #pragma unroll
    for (int c = 0; c < 64; c++) {
        float h2 = fmaxf(acc[c] + b2[c], 0.f);
        s = fmaf(h2, W3[c], s);
    }
    float dff = s - __shfl_xor(s, 1, 64);   // even lane: a1-a2, odd: a2-a1 (same square)
    double dsq = (double)dff * (double)dff;
    #pragma unroll
    for (int m = 1; m <= 32; m <<= 1) dsq += __shfl_xor(dsq, m, 64);
    // each pair counted twice (2 lanes) -> scaled by 0.5 in k3

    __syncthreads();   // all waves done with their A region
    if (lane == 0) ((double*)A)[0] = dsq;
    __syncthreads();
    if (tid == 0) {
        double sum = 0.0;
        #pragma unroll
        for (int w = 0; w < 4; w++) sum += ((double*)&Ash[w][0])[0];
        partials[blockIdx.x] = sum;   // 0..511 pos, 512..1023 neg
    }
}

// ---------------- Kernel 3: final reduction ----------------
__global__ void k3_final(const double* __restrict__ partials, float* __restrict__ out)
{
    int lane = threadIdx.x;  // 64 threads
    double sp = 0.0, sn = 0.0;
    #pragma unroll
    for (int i = 0; i < 8; i++) {
        sp += partials[lane + 64 * i];
        sn += partials[512 + lane + 64 * i];
    }
    #pragma unroll
    for (int m = 1; m <= 32; m <<= 1) {
        sp += __shfl_xor(sp, m, 64);
        sn += __shfl_xor(sn, m, 64);
    }
    if (lane == 0) out[0] = (float)((sp - sn) * 0.5 / (double)NPAIRS);
}

extern "C" void kernel_launch(void* const* d_in, const int* in_sizes, int n_in,
                              void* d_out, int out_size, void* d_ws, size_t ws_size,
                              hipStream_t stream) {
    const int*   pos  = (const int*)d_in[0];
    const int*   neg  = (const int*)d_in[1];
    const float* drug = (const float*)d_in[2];
    const float* tgt  = (const float*)d_in[3];
    const float* W1   = (const float*)d_in[4];
    const float* b1   = (const float*)d_in[5];
    const float* W2   = (const float*)d_in[6];
    const float* b2   = (const float*)d_in[7];
    const float* W3   = (const float*)d_in[8];
    // d_in[9] = b3: cancels in a1 - a2, unused

    float* Dp = (float*)d_ws;
    float* Tp = Dp + NROWS * 128;
    double* partials = (double*)((char*)d_ws + (size_t)(2 * NROWS * 128) * sizeof(float));
    float* out = (float*)d_out;

    k1_precompute<<<2 * K1_BLOCKS, 256, 0, stream>>>(drug, tgt, W1, Dp, Tp);
    k2_pairs<<<1024, 256, 0, stream>>>(Dp, Tp, pos, neg, b1, W2, b2, W3, partials);
    k3_final<<<1, 64, 0, stream>>>(partials, out);
}

// Round 4
// 94.415 us; speedup vs baseline: 2.1856x; 1.1620x over previous
//
#include <hip/hip_runtime.h>

#define EMB 512
#define NROWS 10000
#define NPAIRS 65536

typedef __bf16 bf16x8 __attribute__((ext_vector_type(8)));
typedef float  f32x4  __attribute__((ext_vector_type(4)));
typedef unsigned int u32x4 __attribute__((ext_vector_type(4)));

// Split fp32 pair into packed bf16-hi dword and bf16-lo dword (RNE both).
__device__ __forceinline__ void split2(float x0, float x1, unsigned* hw, unsigned* lw) {
    unsigned u0 = __float_as_uint(x0), u1 = __float_as_uint(x1);
    unsigned r0 = u0 + 0x7FFFu + ((u0 >> 16) & 1u);
    unsigned r1 = u1 + 0x7FFFu + ((u1 >> 16) & 1u);
    float h0 = __uint_as_float(r0 & 0xFFFF0000u);
    float h1 = __uint_as_float(r1 & 0xFFFF0000u);
    float l0 = x0 - h0, l1 = x1 - h1;                 // exact
    unsigned v0 = __float_as_uint(l0), v1 = __float_as_uint(l1);
    unsigned s0 = v0 + 0x7FFFu + ((v0 >> 16) & 1u);
    unsigned s1 = v1 + 0x7FFFu + ((v1 >> 16) & 1u);
    *hw = (r0 >> 16) | (r1 & 0xFFFF0000u);
    *lw = (s0 >> 16) | (s1 & 0xFFFF0000u);
}

// ---------------- Kernel 1: D = drug @ W1[:512,:] + b1, T = tgt @ W1[512:,:] ----------------
// Block 626: pre-fragment W2 into MFMA lane-order bf16 hi/lo arrays W2F[kt][nt][lane][8].
#define K1_BM 32
#define K1_BK 32
#define K1_BLOCKS 313  // ceil(10000/32)

__global__ __launch_bounds__(256)
void k1_precompute(const float* __restrict__ drug, const float* __restrict__ tgt,
                   const float* __restrict__ W1, const float* __restrict__ b1,
                   const float* __restrict__ W2,
                   float* __restrict__ D, float* __restrict__ T,
                   unsigned* __restrict__ W2Fhi, unsigned* __restrict__ W2Flo)
{
    __shared__ float As[K1_BK][K1_BM + 4];
    __shared__ float Bs[K1_BK][132];

    int bid = blockIdx.x, tid = threadIdx.x;

    if (bid == 2 * K1_BLOCKS) {
        // W2F[kt][nt][lane][i]: bf16 of W2[kt*32 + 8*(lane>>4) + i][nt*16 + (lane&15)]
        unsigned short* hi = (unsigned short*)W2Fhi;
        unsigned short* lo = (unsigned short*)W2Flo;
        for (int e = tid; e < 8192; e += 256) {
            int i  = e & 7;
            int l  = (e >> 3) & 63;
            int nt = (e >> 9) & 3;
            int kt = e >> 11;
            int k = kt * 32 + 8 * (l >> 4) + i;
            int n = nt * 16 + (l & 15);
            float x = W2[k * 64 + n];
            unsigned u = __float_as_uint(x);
            unsigned r = u + 0x7FFFu + ((u >> 16) & 1u);
            float hf = __uint_as_float(r & 0xFFFF0000u);
            float lf = x - hf;
            unsigned v = __float_as_uint(lf);
            unsigned s = v + 0x7FFFu + ((v >> 16) & 1u);
            hi[e] = (unsigned short)(r >> 16);
            lo[e] = (unsigned short)(s >> 16);
        }
        return;
    }

    bool isT = bid >= K1_BLOCKS;
    int tb = isT ? bid - K1_BLOCKS : bid;
    const float* emb = isT ? tgt : drug;
    const float* Wb  = W1 + (isT ? EMB * 128 : 0);
    float* out = isT ? T : D;
    int row0 = tb * K1_BM;

    float acc[4][4];
    #pragma unroll
    for (int i = 0; i < 4; i++)
        #pragma unroll
        for (int j = 0; j < 4; j++) acc[i][j] = 0.f;

    int trow0 = (tid >> 5) * 4;
    int tcol0 = (tid & 31) * 4;

    for (int k0 = 0; k0 < EMB; k0 += K1_BK) {
        __syncthreads();
        {
            int r = tid >> 3, k4 = tid & 7;
            int gr = row0 + r;
            float4 v = make_float4(0.f, 0.f, 0.f, 0.f);
            if (gr < NROWS) v = *(const float4*)(emb + gr * EMB + k0 + k4 * 4);
            As[k4 * 4 + 0][r] = v.x; As[k4 * 4 + 1][r] = v.y;
            As[k4 * 4 + 2][r] = v.z; As[k4 * 4 + 3][r] = v.w;
        }
        #pragma unroll
        for (int l = 0; l < 4; l++) {
            int e = tid + l * 256;
            int kk = e >> 5, c4 = e & 31;
            *(float4*)&Bs[kk][c4 * 4] = *(const float4*)(Wb + (k0 + kk) * 128 + c4 * 4);
        }
        __syncthreads();
        #pragma unroll
        for (int kk = 0; kk < K1_BK; kk++) {
            float4 a = *(const float4*)&As[kk][trow0];
            float4 b = *(const float4*)&Bs[kk][tcol0];
            float av[4] = {a.x, a.y, a.z, a.w};
            float bv[4] = {b.x, b.y, b.z, b.w};
            #pragma unroll
            for (int i = 0; i < 4; i++)
                #pragma unroll
                for (int j = 0; j < 4; j++)
                    acc[i][j] = fmaf(av[i], bv[j], acc[i][j]);
        }
    }
    float4 bias = make_float4(0.f, 0.f, 0.f, 0.f);
    if (!isT) bias = *(const float4*)(b1 + tcol0);   // fold b1 into D
    #pragma unroll
    for (int i = 0; i < 4; i++) {
        int gr = row0 + trow0 + i;
        if (gr < NROWS)
            *(float4*)(out + gr * 128 + tcol0) =
                make_float4(acc[i][0] + bias.x, acc[i][1] + bias.y,
                            acc[i][2] + bias.z, acc[i][3] + bias.w);
    }
}

// ---------------- Kernel 2: pair loss via split-bf16 MFMA ----------------
// 1024 blocks x 4 waves. Wave: 32 pairs (one set) = 64 rows, output 64x64, K=128.
// lane = row in phase 1; h1 split to bf16 hi/lo, XOR-swizzled 16B chunks in
// wave-private LDS (16 KB, K in halves). Phase 2: 4Mx4N tiles of
// mfma_f32_16x16x32_bf16, 3 products per tile (hi*hi + hi*lo + lo*hi).
__global__ __launch_bounds__(256, 2)
void k2_pairs(const float* __restrict__ D, const float* __restrict__ T,
              const int* __restrict__ pos, const int* __restrict__ neg,
              const unsigned* __restrict__ W2Fhi, const unsigned* __restrict__ W2Flo,
              const float* __restrict__ b2, const float* __restrict__ W3,
              double* __restrict__ partials)
{
    __shared__ u32x4 Ash[4][1024];   // 64 KB: per-wave 16 KB = 64 rows x 16 chunks x 16 B

    int tid = threadIdx.x;
    int wave = tid >> 6, lane = tid & 63;
    int g = lane >> 4, lm = lane & 15;
    int gw = blockIdx.x * 4 + wave;              // 0..4095
    const int* pairs = (gw < 2048) ? pos : neg;  // blocks 0..511 pos, 512..1023 neg
    int p0 = (gw & 2047) * 32;

    // lane = row r: pair p0 + (r>>1), side r&1
    int p = p0 + (lane >> 1), side = lane & 1;
    int i0 = pairs[p * 3];
    int it = pairs[p * 3 + 1 + side];

    const float4* D4 = (const float4*)D;
    const float4* T4 = (const float4*)T;
    const u32x4* BH4 = (const u32x4*)W2Fhi;
    const u32x4* BL4 = (const u32x4*)W2Flo;
    u32x4* A4w = &Ash[wave][0];

    f32x4 acc[4][4];
    #pragma unroll
    for (int mt = 0; mt < 4; mt++)
        #pragma unroll
        for (int nt = 0; nt < 4; nt++) { acc[mt][nt][0]=0.f; acc[mt][nt][1]=0.f; acc[mt][nt][2]=0.f; acc[mt][nt][3]=0.f; }

    #pragma unroll 1
    for (int half = 0; half < 2; half++) {
        int gbase = half * 16;
        // ---- phase 1: build h1 hi/lo chunks for own row (64 k) ----
        #pragma unroll 4
        for (int c = 0; c < 8; c++) {
            float4 da = D4[i0 * 32 + gbase + c * 2];
            float4 db = D4[i0 * 32 + gbase + c * 2 + 1];
            float4 ta = T4[it * 32 + gbase + c * 2];
            float4 tb = T4[it * 32 + gbase + c * 2 + 1];
            float h0 = fmaxf(da.x + ta.x, 0.f), h1v = fmaxf(da.y + ta.y, 0.f);
            float h2 = fmaxf(da.z + ta.z, 0.f), h3 = fmaxf(da.w + ta.w, 0.f);
            float h4 = fmaxf(db.x + tb.x, 0.f), h5 = fmaxf(db.y + tb.y, 0.f);
            float h6 = fmaxf(db.z + tb.z, 0.f), h7 = fmaxf(db.w + tb.w, 0.f);
            unsigned hq0, hq1, hq2, hq3, lq0, lq1, lq2, lq3;
            split2(h0, h1v, &hq0, &lq0);
            split2(h2, h3,  &hq1, &lq1);
            split2(h4, h5,  &hq2, &lq2);
            split2(h6, h7,  &hq3, &lq3);
            u32x4 hq, lq;
            hq[0] = hq0; hq[1] = hq1; hq[2] = hq2; hq[3] = hq3;
            lq[0] = lq0; lq[1] = lq1; lq[2] = lq2; lq[3] = lq3;
            A4w[lane * 16 + (c ^ lm)]       = hq;
            A4w[lane * 16 + ((8 + c) ^ lm)] = lq;
        }
        asm volatile("s_waitcnt lgkmcnt(0)" ::: "memory");
        // ---- phase 2: MFMA over this half's 2 K-tiles ----
        #pragma unroll
        for (int kt_loc = 0; kt_loc < 2; kt_loc++) {
            int kt = half * 2 + kt_loc;
            u32x4 bh[4], bl[4];
            #pragma unroll
            for (int nt = 0; nt < 4; nt++) {
                bh[nt] = BH4[(kt * 4 + nt) * 64 + lane];
                bl[nt] = BL4[(kt * 4 + nt) * 64 + lane];
            }
            #pragma unroll
            for (int mt = 0; mt < 4; mt++) {
                int rbase = (mt * 16 + lm) * 16;
                u32x4 ah = A4w[rbase + ((kt_loc * 4 + g) ^ lm)];
                u32x4 al = A4w[rbase + ((8 + kt_loc * 4 + g) ^ lm)];
                bf16x8 Ah = __builtin_bit_cast(bf16x8, ah);
                bf16x8 Al = __builtin_bit_cast(bf16x8, al);
                #pragma unroll
                for (int nt = 0; nt < 4; nt++) {
                    bf16x8 Bh = __builtin_bit_cast(bf16x8, bh[nt]);
                    bf16x8 Bl = __builtin_bit_cast(bf16x8, bl[nt]);
                    acc[mt][nt] = __builtin_amdgcn_mfma_f32_16x16x32_bf16(Ah, Bh, acc[mt][nt], 0, 0, 0);
                    acc[mt][nt] = __builtin_amdgcn_mfma_f32_16x16x32_bf16(Ah, Bl, acc[mt][nt], 0, 0, 0);
                    acc[mt][nt] = __builtin_amdgcn_mfma_f32_16x16x32_bf16(Al, Bh, acc[mt][nt], 0, 0, 0);
                }
            }
        }
        asm volatile("s_waitcnt lgkmcnt(0)" ::: "memory");  // reads done before next half's writes
    }

    // ---- epilogue: layer 3 + pair diff ----
    // lane holds D rows mt*16 + 4g + reg? NO: C/D map col=lane&15, row=(lane>>4)*4+reg (m89).
    // Lane (g,lm): holds D rows mt*16 + 4g + reg for reg=0..3? That is row=(lane>>4)*4+reg. Col nt*16+lm.
    float b2v[4], w3v[4];
    #pragma unroll
    for (int nt = 0; nt < 4; nt++) { b2v[nt] = b2[nt * 16 + lm]; w3v[nt] = W3[nt * 16 + lm]; }

    float pr[4][4];
    #pragma unroll
    for (int mt = 0; mt < 4; mt++)
        #pragma unroll
        for (int reg = 0; reg < 4; reg++) {
            float s = 0.f;
            #pragma unroll
            for (int nt = 0; nt < 4; nt++) {
                float h2 = fmaxf(acc[mt][nt][reg] + b2v[nt], 0.f);
                s = fmaf(h2, w3v[nt], s);
            }
            pr[mt][reg] = s;
        }
    // reduce over the 16 lanes sharing g (cols)
    #pragma unroll
    for (int m = 1; m <= 8; m <<= 1)
        #pragma unroll
        for (int mt = 0; mt < 4; mt++)
            #pragma unroll
            for (int reg = 0; reg < 4; reg++)
                pr[mt][reg] += __shfl_xor(pr[mt][reg], m, 64);

    // rows within this lane: r = mt*16 + 4g + reg; pairs are (even,odd) = (reg0,reg1),(reg2,reg3)
    double dsq = 0.0;
    #pragma unroll
    for (int mt = 0; mt < 4; mt++) {
        float d0 = pr[mt][0] - pr[mt][1];
        float d1 = pr[mt][2] - pr[mt][3];
        dsq += (double)d0 * (double)d0 + (double)d1 * (double)d1;
    }
    // sum the 4 g-groups (lanes with same lm hold distinct g contributions)
    dsq += __shfl_xor(dsq, 16, 64);
    dsq += __shfl_xor(dsq, 32, 64);

    __syncthreads();
    if (lane == 0) ((double*)&Ash[wave][0])[0] = dsq;
    __syncthreads();
    if (tid == 0) {
        double sum = 0.0;
        #pragma unroll
        for (int w = 0; w < 4; w++) sum += ((double*)&Ash[w][0])[0];
        partials[blockIdx.x] = sum;   // 0..511 pos, 512..1023 neg
    }
}

// ---------------- Kernel 3: final reduction ----------------
__global__ void k3_final(const double* __restrict__ partials, float* __restrict__ out)
{
    int lane = threadIdx.x;  // 64 threads
    double sp = 0.0, sn = 0.0;
    #pragma unroll
    for (int i = 0; i < 8; i++) {
        sp += partials[lane + 64 * i];
        sn += partials[512 + lane + 64 * i];
    }
    #pragma unroll
    for (int m = 1; m <= 32; m <<= 1) {
        sp += __shfl_xor(sp, m, 64);
        sn += __shfl_xor(sn, m, 64);
    }
    if (lane == 0) out[0] = (float)((sp - sn) / (double)NPAIRS);
}

extern "C" void kernel_launch(void* const* d_in, const int* in_sizes, int n_in,
                              void* d_out, int out_size, void* d_ws, size_t ws_size,
                              hipStream_t stream) {
    const int*   pos  = (const int*)d_in[0];
    const int*   neg  = (const int*)d_in[1];
    const float* drug = (const float*)d_in[2];
    const float* tgt  = (const float*)d_in[3];
    const float* W1   = (const float*)d_in[4];
    const float* b1   = (const float*)d_in[5];
    const float* W2   = (const float*)d_in[6];
    const float* b2   = (const float*)d_in[7];
    const float* W3   = (const float*)d_in[8];
    // d_in[9] = b3: cancels in a1 - a2, unused

    float* Dp = (float*)d_ws;
    float* Tp = Dp + NROWS * 128;
    unsigned* W2Fhi = (unsigned*)(Tp + NROWS * 128);      // 4096 u32 = 16 KB
    unsigned* W2Flo = W2Fhi + 4096;
    double* partials = (double*)(W2Flo + 4096);
    float* out = (float*)d_out;

    k1_precompute<<<2 * K1_BLOCKS + 1, 256, 0, stream>>>(drug, tgt, W1, b1, W2, Dp, Tp, W2Fhi, W2Flo);
    k2_pairs<<<1024, 256, 0, stream>>>(Dp, Tp, pos, neg, W2Fhi, W2Flo, b2, W3, partials);
    k3_final<<<1, 64, 0, stream>>>(partials, out);
}